// Round 1
// baseline (335.308 us; speedup 1.0000x reference)
//
#include <hip/hip_runtime.h>
#include <hip/hip_cooperative_groups.h>

namespace cg = cooperative_groups;

// Problem constants
#define E_TOT 8192
#define NB    32
#define H     128
#define EPG   256          // edges per graph (contiguous slots)
#define NDT   34           // 32 edge-attr dims + 1 bias row + 1 root block
#define YD    33           // Y keeps only d<33 (root fused into h)
#define YCOLS (YD * H)     // 4224

typedef __attribute__((ext_vector_type(8))) short bf16x8;
typedef __attribute__((ext_vector_type(4))) float f32x4;

__device__ __forceinline__ unsigned short bf16_rne(float f) {
    unsigned int u = __float_as_uint(f);
    unsigned int r = (u + 0x7FFFu + ((u >> 16) & 1u)) >> 16;
    return (unsigned short)r;
}
__device__ __forceinline__ float bf16_to_f32(unsigned short h) {
    return __uint_as_float(((unsigned int)h) << 16);
}

__device__ __forceinline__ void gload_lds16(const void* g, void* l) {
    __builtin_amdgcn_global_load_lds(
        (const __attribute__((address_space(1))) unsigned int*)g,
        (__attribute__((address_space(3))) unsigned int*)l, 16, 0, 0);
}

// ---------------------------------------------------------------------------
// Shared-memory union: one 20.5 KB block reused by every phase.
// alignas(16): uint4 / bf16x8 accesses require 16B alignment.
// ---------------------------------------------------------------------------
union alignas(16) SMem {
    struct { unsigned short LHI[128][40]; unsigned short LLO[128][40]; } bt; // 20480 B
    struct { unsigned short A[128 * 32]; unsigned short B[128 * 32]; } gm;   // 16384 B
    struct { float sh[256]; } bn;                                            // 1024 B
    struct {
        float muL[128], rsL[128], gmL[128], btL[128], pwL[128];
        float scoreL[128], red[128];
        int   mapL[128];
        float sinv;
        float gmean[128], h1c[64];
    } pool;                                                                  // ~4.9 KB
};

// ---------------------------------------------------------------------------
// Phase bodies as device functions (ported verbatim from the standalone
// kernels; grid-stride where the old grid was larger than the coop grid).
// ---------------------------------------------------------------------------

// One build_Bt "unit" == one old block: (d, i0) transposes a 32x128 slab.
template<int CIN>
__device__ void bt_unit(SMem& sm, const float* __restrict__ nnw,
                        const float* __restrict__ nnb, const float* __restrict__ root,
                        unsigned short* __restrict__ Bt, int d, int i0)
{
    const int tid = threadIdx.x;
    const float* __restrict__ W =
        (d < 32) ? (nnw + (size_t)d * CIN * 128) : ((d == 32) ? nnb : root);

    for (int idx = tid; idx < 32 * 128; idx += 256) {
        const int ii = idx >> 7, o = idx & 127;
        const float val = W[(size_t)(i0 + ii) * 128 + o];
        const unsigned short h = bf16_rne(val);
        const unsigned short l = bf16_rne(val - bf16_to_f32(h));
        sm.bt.LHI[o][ii] = h; sm.bt.LLO[o][ii] = l;
    }
    __syncthreads();

    const int o    = tid & 127;
    const int half = tid >> 7;
    unsigned short* dst = Bt + (size_t)(d * 128 + o) * (3 * CIN);
    const uint4* hs = (const uint4*)&sm.bt.LHI[o][0];
    const uint4* ls = (const uint4*)&sm.bt.LLO[o][0];
    if (half == 0) {
        uint4* p = (uint4*)(dst + i0);
        p[0] = hs[0]; p[1] = hs[1]; p[2] = hs[2]; p[3] = hs[3];
        uint4* q = (uint4*)(dst + 2 * CIN + i0);
        q[0] = ls[0]; q[1] = ls[1]; q[2] = ls[2]; q[3] = ls[3];
    } else {
        uint4* p = (uint4*)(dst + CIN + i0);
        p[0] = hs[0]; p[1] = hs[1]; p[2] = hs[2]; p[3] = hs[3];
    }
    __syncthreads();   // next unit reuses LHI/LLO
}

// 128x128 bf16-MFMA tile of A'[M,K3] @ Bt'[N,K3]^T, grid-strided over tiles.
template<int K3>
__device__ void ygemm_phase(SMem& sm, int nb, int bid,
                            const unsigned short* __restrict__ A,
                            const unsigned short* __restrict__ Bt,
                            float* __restrict__ Y,
                            const float* __restrict__ bias,
                            float* __restrict__ hout,
                            int xblocks)
{
    const int lane = threadIdx.x & 63;
    const int w    = threadIdx.x >> 6;
    const int wm = w >> 1, wn = w & 1;
    const int arow = lane >> 2;
    const int acol = (lane & 3) * 8;
    const int koff = (lane >> 4) * 8;
    const int mrow = lane & 15;
    const int crow = (lane >> 4) * 4;
    const int ccol = lane & 15;

    const int total = xblocks * NDT;
    for (int t = bid; t < total; t += nb) {
        const int bx = t / NDT, by = t % NDT;
        const int v0 = bx * 128, n0 = by * 128;

        f32x4 acc[4][4];
        #pragma unroll
        for (int i = 0; i < 4; ++i)
            #pragma unroll
            for (int j = 0; j < 4; ++j)
                acc[i][j] = (f32x4)(0.0f);

        for (int k0 = 0; k0 < K3; k0 += 32) {
            __syncthreads();
            #pragma unroll
            for (int tt = 0; tt < 2; ++tt) {
                const int c = w * 2 + tt;
                const int r = c * 16 + arow;
                gload_lds16(A  + (size_t)(v0 + r) * K3 + k0 + acol, &sm.gm.A[c * 512]);
                gload_lds16(Bt + (size_t)(n0 + r) * K3 + k0 + acol, &sm.gm.B[c * 512]);
            }
            __syncthreads();

            bf16x8 a[4], b[4];
            #pragma unroll
            for (int f = 0; f < 4; ++f) {
                a[f] = *(const bf16x8*)&sm.gm.A[(wm * 64 + f * 16 + mrow) * 32 + koff];
                b[f] = *(const bf16x8*)&sm.gm.B[(wn * 64 + f * 16 + mrow) * 32 + koff];
            }
            #pragma unroll
            for (int fm = 0; fm < 4; ++fm)
                #pragma unroll
                for (int fn = 0; fn < 4; ++fn)
                    acc[fm][fn] = __builtin_amdgcn_mfma_f32_16x16x32_bf16(
                        a[fm], b[fn], acc[fm][fn], 0, 0, 0);
        }

        const bool is_root = (by == YD);
        #pragma unroll
        for (int fm = 0; fm < 4; ++fm) {
            const int gr = v0 + wm * 64 + fm * 16 + crow;
            #pragma unroll
            for (int fn = 0; fn < 4; ++fn) {
                const int col = wn * 64 + fn * 16 + ccol;
                if (is_root) {
                    const float bv = bias[col];
                    #pragma unroll
                    for (int r = 0; r < 4; ++r)
                        hout[(size_t)(gr + r) * H + col] = acc[fm][fn][r] + bv;
                } else {
                    const size_t gc = (size_t)by * H + col;
                    #pragma unroll
                    for (int r = 0; r < 4; ++r)
                        Y[(size_t)(gr + r) * YCOLS + gc] = acc[fm][fn][r];
                }
            }
        }
    }
}

// h[dst[e], :] += sum_{d<32} ea[e,d]*Y[src[e],d,:] + Y[src[e],32,:]
// NOTE: guard, not early-return — every thread must reach the next grid.sync.
__device__ void contract_phase(int nb, int bid,
                               const float* __restrict__ Y,
                               const float* __restrict__ ea,
                               const int*   __restrict__ esrc,
                               const int*   __restrict__ edst,
                               float*       __restrict__ agg)
{
    const int grp = threadIdx.x >> 5;
    const int l5  = threadIdx.x & 31;
    for (int b = bid; b < E_TOT / 8; b += nb) {
        const int e = b * 8 + grp;
        const int s = esrc[e];
        if (s >= 0) {
            const float* yb  = Y + (size_t)s * YCOLS + l5 * 4;
            const float* ear = ea + (size_t)e * 32;

            float4 acc = *reinterpret_cast<const float4*>(yb + 32 * H);
            #pragma unroll 8
            for (int dd = 0; dd < 32; ++dd) {
                const float c = ear[dd];
                const float4 y = *reinterpret_cast<const float4*>(yb + dd * H);
                acc.x += c * y.x; acc.y += c * y.y; acc.z += c * y.z; acc.w += c * y.w;
            }
            float* out = agg + (size_t)edst[e] * H + l5 * 4;
            atomicAdd(out + 0, acc.x);
            atomicAdd(out + 1, acc.y);
            atomicAdd(out + 2, acc.z);
            atomicAdd(out + 3, acc.w);
        }
    }
}

__device__ void bn_phase(SMem& sm, int nb, int bid,
                         const float* __restrict__ hbuf, int n,
                         float* __restrict__ gsum, float* __restrict__ gsumsq)
{
    const int tid   = threadIdx.x;
    const int col   = tid & 127;
    const int rhalf = tid >> 7;
    float s = 0.f, sq = 0.f;
    for (int r = bid * 2 + rhalf; r < n; r += nb * 2) {
        float v = hbuf[(size_t)r * H + col];
        s += v; sq += v * v;
    }
    sm.bn.sh[tid] = s;  __syncthreads();
    if (rhalf == 0) s += sm.bn.sh[tid + 128];
    __syncthreads();
    sm.bn.sh[tid] = sq; __syncthreads();
    const bool active = (bid * 2 < n);
    if (rhalf == 0 && active) {
        sq += sm.bn.sh[tid + 128];
        atomicAdd(&gsum[col], s);
        atomicAdd(&gsumsq[col], sq);
    }
    __syncthreads();
}

__device__ void pool_phase(SMem& sm, int g,
                           const float* __restrict__ hbuf,
                           const float* __restrict__ gsum, const float* __restrict__ gsumsq,
                           float n_f,
                           const float* __restrict__ gamma, const float* __restrict__ beta,
                           const float* __restrict__ pw,
                           int npg, int k,
                           const int* __restrict__ esrc_in, const int* __restrict__ edst_in,
                           int* __restrict__ esrc_out, int* __restrict__ edst_out,
                           unsigned short* __restrict__ Aout)
{
    const int tid = threadIdx.x;
    const int wv  = tid >> 6;
    const int ln  = tid & 63;
    auto& P = sm.pool;

    if (tid < 128) {
        const float mu  = gsum[tid] / n_f;
        const float var = gsumsq[tid] / n_f - mu * mu;
        P.muL[tid] = mu;
        P.rsL[tid] = rsqrtf(var + 1e-5f);
        P.gmL[tid] = gamma[tid];
        P.btL[tid] = beta[tid];
        const float p = pw[tid];
        P.pwL[tid] = p;
        P.red[tid] = p * p;
    }
    __syncthreads();
    for (int off = 64; off > 0; off >>= 1) {
        if (tid < off) P.red[tid] += P.red[tid + off];
        __syncthreads();
    }
    if (tid == 0) P.sinv = rsqrtf(P.red[0]);
    __syncthreads();

    for (int r = wv; r < npg; r += 4) {
        const float* hr = hbuf + (size_t)(g * npg + r) * H;
        float p = 0.f;
        #pragma unroll
        for (int half = 0; half < 2; ++half) {
            const int c = ln + half * 64;
            const float y = fmaxf(P.gmL[c] * (hr[c] - P.muL[c]) * P.rsL[c] + P.btL[c], 0.f);
            p += y * P.pwL[c];
        }
        #pragma unroll
        for (int off = 32; off > 0; off >>= 1)
            p += __shfl_down(p, off, 64);
        if (ln == 0) P.scoreL[r] = tanhf(p * P.sinv);
    }
    __syncthreads();

    if (tid < npg) {
        const float si = P.scoreL[tid];
        int cnt = 0;
        for (int j = 0; j < npg; ++j) {
            const float sj = P.scoreL[j];
            cnt += (sj > si) || (sj == si && j < tid);
        }
        P.mapL[tid] = (cnt < k) ? cnt : -1;
    }
    __syncthreads();

    for (int r = wv; r < npg; r += 4) {
        const int nr = P.mapL[r];
        if (nr < 0) continue;
        const float sc = P.scoreL[r];
        const float* hr = hbuf + (size_t)(g * npg + r) * H;
        unsigned short* arow = Aout + (size_t)(g * k + nr) * 384;
        #pragma unroll
        for (int half = 0; half < 2; ++half) {
            const int c = ln + half * 64;
            const float y = fmaxf(P.gmL[c] * (hr[c] - P.muL[c]) * P.rsL[c] + P.btL[c], 0.f) * sc;
            const unsigned short hb = bf16_rne(y);
            const unsigned short lb = bf16_rne(y - bf16_to_f32(hb));
            arow[c] = hb; arow[128 + c] = hb; arow[256 + c] = lb;
        }
    }

    {
        const int e = g * EPG + tid;
        const int s = esrc_in[e];
        int ns = -1, nd = -1;
        if (s >= 0) {
            const int ms = P.mapL[s - g * npg];
            const int md = P.mapL[edst_in[e] - g * npg];
            if (ms >= 0 && md >= 0) { ns = g * k + ms; nd = g * k + md; }
        }
        esrc_out[e] = ns; edst_out[e] = nd;
    }
    __syncthreads();
}

__device__ void pool_final_phase(SMem& sm, int g,
                                 const float* __restrict__ hbuf,
                                 const float* __restrict__ gsum, const float* __restrict__ gsumsq,
                                 float n_f,
                                 const float* __restrict__ gamma, const float* __restrict__ beta,
                                 const float* __restrict__ pw,
                                 const float* __restrict__ lin1_w, const float* __restrict__ lin1_b,
                                 const float* __restrict__ lin2_w, const float* __restrict__ lin2_b,
                                 float* __restrict__ out)
{
    const int tid = threadIdx.x;
    const int wv  = tid >> 6;
    const int ln  = tid & 63;
    const int npg = 32, k = 16;
    auto& P = sm.pool;

    if (tid < 128) {
        const float mu  = gsum[tid] / n_f;
        const float var = gsumsq[tid] / n_f - mu * mu;
        P.muL[tid] = mu;
        P.rsL[tid] = rsqrtf(var + 1e-5f);
        P.gmL[tid] = gamma[tid];
        P.btL[tid] = beta[tid];
        const float p = pw[tid];
        P.pwL[tid] = p;
        P.red[tid] = p * p;
    }
    __syncthreads();
    for (int off = 64; off > 0; off >>= 1) {
        if (tid < off) P.red[tid] += P.red[tid + off];
        __syncthreads();
    }
    if (tid == 0) P.sinv = rsqrtf(P.red[0]);
    __syncthreads();

    for (int r = wv; r < npg; r += 4) {
        const float* hr = hbuf + (size_t)(g * npg + r) * H;
        float p = 0.f;
        #pragma unroll
        for (int half = 0; half < 2; ++half) {
            const int c = ln + half * 64;
            const float y = fmaxf(P.gmL[c] * (hr[c] - P.muL[c]) * P.rsL[c] + P.btL[c], 0.f);
            p += y * P.pwL[c];
        }
        #pragma unroll
        for (int off = 32; off > 0; off >>= 1)
            p += __shfl_down(p, off, 64);
        if (ln == 0) P.scoreL[r] = tanhf(p * P.sinv);
    }
    __syncthreads();

    if (tid < npg) {
        const float si = P.scoreL[tid];
        int cnt = 0;
        for (int j = 0; j < npg; ++j) {
            const float sj = P.scoreL[j];
            cnt += (sj > si) || (sj == si && j < tid);
        }
        P.mapL[tid] = (cnt < k) ? cnt : -1;
    }
    __syncthreads();

    if (tid < 128) {
        float acc = 0.f;
        for (int r = 0; r < npg; ++r) {
            if (P.mapL[r] < 0) continue;
            const float hv = hbuf[(size_t)(g * npg + r) * H + tid];
            const float y  = fmaxf(P.gmL[tid] * (hv - P.muL[tid]) * P.rsL[tid] + P.btL[tid], 0.f);
            acc += y * P.scoreL[r];
        }
        P.gmean[tid] = acc * (1.0f / 16.0f);
    }
    __syncthreads();

    if (tid < 64) {
        float acc = lin1_b[tid];
        for (int o = 0; o < 128; ++o) acc += P.gmean[o] * lin1_w[o * 64 + tid];
        P.h1c[tid] = fmaxf(acc, 0.f);
    }
    __syncthreads();
    if (tid == 0) {
        float z = lin2_b[0];
        for (int j = 0; j < 64; ++j) z += P.h1c[j] * lin2_w[j];
        out[g] = 1.0f / (1.0f + expf(-z));
    }
}

// ---------------------------------------------------------------------------
// The cooperative mega-kernel: entire pipeline, 13 grid syncs, 1 dispatch.
// __launch_bounds__(256,3): 3 blocks/CU (12 waves/CU) -> grid 768 co-resident.
// ---------------------------------------------------------------------------
struct KParams {
    const float *x, *eattr;
    const int *ei_src, *ei_dst;
    const float *nn1_w, *nn1_b, *root1, *bias1;
    const float *nn2_w, *nn2_b, *root2, *bias2;
    const float *nn3_w, *nn3_b, *root3, *bias3;
    const float *gamma1, *beta1, *gamma2, *beta2, *gamma3, *beta3;
    const float *pw1, *pw2, *pw3;
    const float *lin1_w, *lin1_b, *lin2_w, *lin2_b;
    float *h1, *h2, *h3, *stats, *Y;
    int *src1, *dst1, *src2, *dst2;
    unsigned short *A1, *A2, *A3, *Bt1, *Bt2, *Bt3;
    float *out;
};

__global__ __launch_bounds__(256, 3)
void mega(KParams p)
{
    cg::grid_group grid = cg::this_grid();
    __shared__ SMem sm;
    const int nb  = (int)gridDim.x;
    const int bid = (int)blockIdx.x;
    const int tid = (int)threadIdx.x;

    // ---- phase 0: weight prep (Bt1/Bt2/Bt3), build A1, zero stats ----
    for (int u = bid; u < 340; u += nb) {
        if (u < 68)       bt_unit<64 >(sm, p.nn1_w, p.nn1_b, p.root1, p.Bt1, u >> 1, (u & 1) * 32);
        else if (u < 204) { const int t = u - 68;  bt_unit<128>(sm, p.nn2_w, p.nn2_b, p.root2, p.Bt2, t >> 2, (t & 3) * 32); }
        else              { const int t = u - 204; bt_unit<128>(sm, p.nn3_w, p.nn3_b, p.root3, p.Bt3, t >> 2, (t & 3) * 32); }
    }
    for (int idx = bid * 256 + tid; idx < 4096 * 64; idx += nb * 256) {
        const int v = idx >> 6, i = idx & 63;
        const float val = p.x[idx];
        const unsigned short h = bf16_rne(val);
        const unsigned short l = bf16_rne(val - bf16_to_f32(h));
        unsigned short* row = p.A1 + (size_t)v * 192;
        row[i] = h; row[64 + i] = h; row[128 + i] = l;
    }
    for (int idx = bid * 256 + tid; idx < 6 * 128; idx += nb * 256) p.stats[idx] = 0.f;
    grid.sync();

    // ---- stage 1 ----
    ygemm_phase<192>(sm, nb, bid, p.A1, p.Bt1, p.Y, p.bias1, p.h1, 32);
    grid.sync();
    contract_phase(nb, bid, p.Y, p.eattr, p.ei_src, p.ei_dst, p.h1);
    grid.sync();
    bn_phase(sm, nb, bid, p.h1, 4096, p.stats, p.stats + 128);
    grid.sync();
    if (bid < NB)
        pool_phase(sm, bid, p.h1, p.stats, p.stats + 128, 4096.0f,
                   p.gamma1, p.beta1, p.pw1, 128, 64,
                   p.ei_src, p.ei_dst, p.src1, p.dst1, p.A2);
    grid.sync();

    // ---- stage 2 ----
    ygemm_phase<384>(sm, nb, bid, p.A2, p.Bt2, p.Y, p.bias2, p.h2, 16);
    grid.sync();
    contract_phase(nb, bid, p.Y, p.eattr, p.src1, p.dst1, p.h2);
    grid.sync();
    bn_phase(sm, nb, bid, p.h2, 2048, p.stats + 256, p.stats + 384);
    grid.sync();
    if (bid < NB)
        pool_phase(sm, bid, p.h2, p.stats + 256, p.stats + 384, 2048.0f,
                   p.gamma2, p.beta2, p.pw2, 64, 32,
                   p.src1, p.dst1, p.src2, p.dst2, p.A3);
    grid.sync();

    // ---- stage 3 ----
    ygemm_phase<384>(sm, nb, bid, p.A3, p.Bt3, p.Y, p.bias3, p.h3, 8);
    grid.sync();
    contract_phase(nb, bid, p.Y, p.eattr, p.src2, p.dst2, p.h3);
    grid.sync();
    bn_phase(sm, nb, bid, p.h3, 1024, p.stats + 512, p.stats + 640);
    grid.sync();
    if (bid < NB)
        pool_final_phase(sm, bid, p.h3, p.stats + 512, p.stats + 640, 1024.0f,
                         p.gamma3, p.beta3, p.pw3,
                         p.lin1_w, p.lin1_b, p.lin2_w, p.lin2_b, p.out);
}

// ===========================================================================
// Fallback path: original standalone kernels (kept verbatim; used only if the
// cooperative launch is unavailable).
// ===========================================================================
template<int CIN>
__global__ __launch_bounds__(128)
void build_A(const float* __restrict__ x, unsigned short* __restrict__ A)
{
    const int v = blockIdx.x;
    unsigned short* row = A + (size_t)v * (3 * CIN);
    for (int i = threadIdx.x; i < CIN; i += 128) {
        const float val = x[(size_t)v * CIN + i];
        const unsigned short h = bf16_rne(val);
        const unsigned short l = bf16_rne(val - bf16_to_f32(h));
        row[i] = h; row[CIN + i] = h; row[2 * CIN + i] = l;
    }
}

template<int CIN>
__global__ __launch_bounds__(256)
void build_Bt(const float* __restrict__ nnw, const float* __restrict__ nnb,
              const float* __restrict__ root, unsigned short* __restrict__ Bt)
{
    __shared__ SMem sm;
    bt_unit<CIN>(sm, nnw, nnb, root, Bt, blockIdx.x, blockIdx.y * 32);
}

template<int K3>
__global__ __launch_bounds__(256)
void ygemm_k(const unsigned short* __restrict__ A, const unsigned short* __restrict__ Bt,
             float* __restrict__ Y, const float* __restrict__ bias, float* __restrict__ h,
             int xblocks)
{
    __shared__ SMem sm;
    const int t = blockIdx.x;       // one tile per block
    ygemm_phase<K3>(sm, xblocks * NDT, t, A, Bt, Y, bias, h, xblocks);
}

__global__ __launch_bounds__(256)
void contract_k(const float* __restrict__ Y, const float* __restrict__ ea,
                const int* __restrict__ esrc, const int* __restrict__ edst,
                float* __restrict__ agg)
{
    contract_phase(E_TOT / 8, blockIdx.x, Y, ea, esrc, edst, agg);
}

__global__ __launch_bounds__(256)
void bn_k(const float* __restrict__ h, int n, float* __restrict__ gsum,
          float* __restrict__ gsumsq)
{
    __shared__ SMem sm;
    bn_phase(sm, gridDim.x, blockIdx.x, h, n, gsum, gsumsq);
}

__global__ __launch_bounds__(256)
void pool_k(const float* __restrict__ h, const float* __restrict__ gsum,
            const float* __restrict__ gsumsq, float n_f,
            const float* __restrict__ gamma, const float* __restrict__ beta,
            const float* __restrict__ pw, int npg, int k,
            const int* __restrict__ esrc_in, const int* __restrict__ edst_in,
            int* __restrict__ esrc_out, int* __restrict__ edst_out,
            unsigned short* __restrict__ Aout)
{
    __shared__ SMem sm;
    pool_phase(sm, blockIdx.x, h, gsum, gsumsq, n_f, gamma, beta, pw, npg, k,
               esrc_in, edst_in, esrc_out, edst_out, Aout);
}

__global__ __launch_bounds__(256)
void pool_final_k(const float* __restrict__ h, const float* __restrict__ gsum,
                  const float* __restrict__ gsumsq, float n_f,
                  const float* __restrict__ gamma, const float* __restrict__ beta,
                  const float* __restrict__ pw,
                  const float* __restrict__ lin1_w, const float* __restrict__ lin1_b,
                  const float* __restrict__ lin2_w, const float* __restrict__ lin2_b,
                  float* __restrict__ out)
{
    __shared__ SMem sm;
    pool_final_phase(sm, blockIdx.x, h, gsum, gsumsq, n_f, gamma, beta, pw,
                     lin1_w, lin1_b, lin2_w, lin2_b, out);
}

// ---------------------------------------------------------------------------
extern "C" void kernel_launch(void* const* d_in, const int* in_sizes, int n_in,
                              void* d_out, int out_size, void* d_ws, size_t ws_size,
                              hipStream_t stream)
{
    const float* x        = (const float*)d_in[0];
    const int*   ei       = (const int*)  d_in[1];
    const float* eattr    = (const float*)d_in[2];
    const float* nn1_w    = (const float*)d_in[4];
    const float* nn1_b    = (const float*)d_in[5];
    const float* root1    = (const float*)d_in[6];
    const float* bias1    = (const float*)d_in[7];
    const float* nn2_w    = (const float*)d_in[8];
    const float* nn2_b    = (const float*)d_in[9];
    const float* root2    = (const float*)d_in[10];
    const float* bias2    = (const float*)d_in[11];
    const float* nn3_w    = (const float*)d_in[12];
    const float* nn3_b    = (const float*)d_in[13];
    const float* root3    = (const float*)d_in[14];
    const float* bias3    = (const float*)d_in[15];
    const float* gamma1   = (const float*)d_in[16];
    const float* beta1    = (const float*)d_in[17];
    const float* gamma2   = (const float*)d_in[18];
    const float* beta2    = (const float*)d_in[19];
    const float* gamma3   = (const float*)d_in[20];
    const float* beta3    = (const float*)d_in[21];
    const float* pw1      = (const float*)d_in[22];
    const float* pw2      = (const float*)d_in[23];
    const float* pw3      = (const float*)d_in[24];
    const float* lin1_w   = (const float*)d_in[25];
    const float* lin1_b   = (const float*)d_in[26];
    const float* lin2_w   = (const float*)d_in[27];
    const float* lin2_b   = (const float*)d_in[28];

    const int* ei_src = ei;
    const int* ei_dst = ei + E_TOT;

    char* wp = (char*)d_ws;
    auto alloc = [&](size_t bytes) { char* p = wp; wp += (bytes + 255) & ~(size_t)255; return p; };
    float* h1   = (float*)alloc(4096 * 128 * 4);
    float* h2   = (float*)alloc(2048 * 128 * 4);
    float* h3   = (float*)alloc(1024 * 128 * 4);
    int*   src1 = (int*)alloc(E_TOT * 4);
    int*   dst1 = (int*)alloc(E_TOT * 4);
    int*   src2 = (int*)alloc(E_TOT * 4);
    int*   dst2 = (int*)alloc(E_TOT * 4);
    float* stats = (float*)alloc(6 * 128 * 4);
    unsigned short* A1  = (unsigned short*)alloc((size_t)4096 * 192 * 2);
    unsigned short* A2  = (unsigned short*)alloc((size_t)2048 * 384 * 2);
    unsigned short* A3  = (unsigned short*)alloc((size_t)1024 * 384 * 2);
    unsigned short* Bt1 = (unsigned short*)alloc((size_t)4352 * 192 * 2);
    unsigned short* Bt2 = (unsigned short*)alloc((size_t)4352 * 384 * 2);
    unsigned short* Bt3 = (unsigned short*)alloc((size_t)4352 * 384 * 2);
    float* Ybuf = (float*)alloc((size_t)4096 * YCOLS * 4);   // 69 MB

    // ---- cooperative single-dispatch path ----
    static int s_grid = -1;
    if (s_grid < 0) {
        int mb = 0;
        if (hipOccupancyMaxActiveBlocksPerMultiprocessor(&mb, mega, 256, 0) != hipSuccess)
            mb = 0;
        int g = mb * 256;                 // 256 CUs on MI355X
        if (g > 768) g = 768;
        s_grid = (g >= 64) ? g : 0;       // need >=NB blocks for pool phases
    }

    if (s_grid > 0) {
        KParams hp;
        hp.x = x; hp.eattr = eattr; hp.ei_src = ei_src; hp.ei_dst = ei_dst;
        hp.nn1_w = nn1_w; hp.nn1_b = nn1_b; hp.root1 = root1; hp.bias1 = bias1;
        hp.nn2_w = nn2_w; hp.nn2_b = nn2_b; hp.root2 = root2; hp.bias2 = bias2;
        hp.nn3_w = nn3_w; hp.nn3_b = nn3_b; hp.root3 = root3; hp.bias3 = bias3;
        hp.gamma1 = gamma1; hp.beta1 = beta1; hp.gamma2 = gamma2; hp.beta2 = beta2;
        hp.gamma3 = gamma3; hp.beta3 = beta3;
        hp.pw1 = pw1; hp.pw2 = pw2; hp.pw3 = pw3;
        hp.lin1_w = lin1_w; hp.lin1_b = lin1_b; hp.lin2_w = lin2_w; hp.lin2_b = lin2_b;
        hp.h1 = h1; hp.h2 = h2; hp.h3 = h3; hp.stats = stats; hp.Y = Ybuf;
        hp.src1 = src1; hp.dst1 = dst1; hp.src2 = src2; hp.dst2 = dst2;
        hp.A1 = A1; hp.A2 = A2; hp.A3 = A3; hp.Bt1 = Bt1; hp.Bt2 = Bt2; hp.Bt3 = Bt3;
        hp.out = (float*)d_out;

        void* args[] = { &hp };
        hipError_t e = hipLaunchCooperativeKernel(mega, dim3(s_grid), dim3(256),
                                                  args, 0, stream);
        if (e == hipSuccess) return;
        s_grid = 0;   // cooperative launch unavailable -> fall through forever
    }

    // ---- fallback: original multi-kernel path ----
    hipMemsetAsync(stats, 0, 6 * 128 * sizeof(float), stream);

    build_Bt<64> <<<dim3(NDT, 2), 256, 0, stream>>>(nn1_w, nn1_b, root1, Bt1);
    build_Bt<128><<<dim3(NDT, 4), 256, 0, stream>>>(nn2_w, nn2_b, root2, Bt2);
    build_Bt<128><<<dim3(NDT, 4), 256, 0, stream>>>(nn3_w, nn3_b, root3, Bt3);
    build_A<64><<<4096, 128, 0, stream>>>(x, A1);

    ygemm_k<192><<<32 * NDT, 256, 0, stream>>>(A1, Bt1, Ybuf, bias1, h1, 32);
    contract_k<<<E_TOT / 8, 256, 0, stream>>>(Ybuf, eattr, ei_src, ei_dst, h1);
    bn_k<<<64, 256, 0, stream>>>(h1, 4096, stats, stats + 128);
    pool_k<<<NB, 256, 0, stream>>>(h1, stats, stats + 128, 4096.0f,
                                   gamma1, beta1, pw1, 128, 64,
                                   ei_src, ei_dst, src1, dst1, A2);

    ygemm_k<384><<<16 * NDT, 256, 0, stream>>>(A2, Bt2, Ybuf, bias2, h2, 16);
    contract_k<<<E_TOT / 8, 256, 0, stream>>>(Ybuf, eattr, src1, dst1, h2);
    bn_k<<<64, 256, 0, stream>>>(h2, 2048, stats + 256, stats + 384);
    pool_k<<<NB, 256, 0, stream>>>(h2, stats + 256, stats + 384, 2048.0f,
                                   gamma2, beta2, pw2, 64, 32,
                                   src1, dst1, src2, dst2, A3);

    ygemm_k<384><<<8 * NDT, 256, 0, stream>>>(A3, Bt3, Ybuf, bias3, h3, 8);
    contract_k<<<E_TOT / 8, 256, 0, stream>>>(Ybuf, eattr, src2, dst2, h3);
    bn_k<<<64, 256, 0, stream>>>(h3, 1024, stats + 512, stats + 640);
    pool_final_k<<<NB, 256, 0, stream>>>(h3, stats + 512, stats + 640, 1024.0f,
                                         gamma3, beta3, pw3,
                                         lin1_w, lin1_b, lin2_w, lin2_b,
                                         (float*)d_out);
}